// Round 3
// baseline (715.607 us; speedup 1.0000x reference)
//
#include <hip/hip_runtime.h>
#include <cstdint>
#include <cstddef>

#define B_    1024
#define L_    200
#define DIN_  256
#define DOUT_ 256
#define K_    8
#define M_    (B_ * L_)   // 204800

typedef __attribute__((ext_vector_type(8))) short bf16x8;
typedef __attribute__((ext_vector_type(4))) float f32x4;

__device__ __forceinline__ float bf2f(unsigned short u) {
  union { unsigned int i; float f; } w; w.i = ((unsigned int)u) << 16; return w.f;
}
__device__ __forceinline__ unsigned short f2bf(float f) {
  union { float f; unsigned int i; } w; w.f = f;
  unsigned int x = w.i;
  return (unsigned short)((x + 0x7fffu + ((x >> 16) & 1u)) >> 16);
}

// ---------------- kernel 0: split W into bf16 hi/mid/lo in MFMA FRAGMENT ORDER.
__global__ __launch_bounds__(256)
void wt_prep(const float* __restrict__ W, unsigned short* __restrict__ Wh,
             unsigned short* __restrict__ Wm, unsigned short* __restrict__ Wl)
{
  const int k = blockIdx.x;    // 256
  const int n = threadIdx.x;   // 256
  float x = W[k * DOUT_ + n];
  unsigned short h = f2bf(x);
  float r = x - bf2f(h);
  unsigned short m = f2bf(r);
  float r2 = r - bf2f(m);
  unsigned short l = f2bf(r2);
  const int k0b = k >> 5, quad = (k >> 3) & 3, j = k & 7;
  const int nt = n >> 4, lr = n & 15;
  const size_t idx = ((((size_t)k0b * 16 + nt) * 64) + (quad * 16 + lr)) * 8 + j;
  Wh[idx] = h;
  Wm[idx] = m;
  Wl[idx] = l;
}

// ---------------- kernel 1: mapped = A @ W via bf16x3-split MFMA.
// R3 retile: wave = 32x128 (acc 64 regs), block = 64x256 (4 waves: 2 M-subtiles
// x 2 N-halves), launch_bounds(256,3) -> 3 waves/SIMD for latency hiding.
// Same 4-slot rolling B prefetch; identical MFMA math/order (bit-identical output).
__global__ __launch_bounds__(256, 3)
void gemm_mapped(const float* __restrict__ A,
                 const unsigned short* __restrict__ Wh,
                 const unsigned short* __restrict__ Wm,
                 const unsigned short* __restrict__ Wl,
                 float* __restrict__ C)
{
  const int t    = threadIdx.x;
  const int wave = t >> 6;
  const int lane = t & 63;
  const int quad = lane >> 4;
  const int lr   = lane & 15;
  const int m0   = blockIdx.x * 64 + (wave & 1) * 32;
  const int nt0  = (wave >> 1) * 8;   // N-half: fragments nt0..nt0+7

  f32x4 acc[2][8];
  #pragma unroll
  for (int mt = 0; mt < 2; ++mt)
    #pragma unroll
    for (int nt = 0; nt < 8; ++nt)
      acc[mt][nt] = (f32x4){0.f, 0.f, 0.f, 0.f};

  bf16x8 Bh[4], Bm[4], Bl[4];
  bf16x8 ah[2], am[2], al[2];
  float4 Af[2][2];

#define BLOAD(K0B, NT, S) do { \
    const size_t _off = (((size_t)(K0B) * 16 + nt0 + (NT)) * 64 + lane) * 8; \
    Bh[S] = *(const bf16x8*)(Wh + _off); \
    Bm[S] = *(const bf16x8*)(Wm + _off); \
    Bl[S] = *(const bf16x8*)(Wl + _off); \
  } while (0)

  const float* ap0 = A + (size_t)(m0 + lr) * DIN_ + quad * 8;
  const float* ap1 = A + (size_t)(m0 + 16 + lr) * DIN_ + quad * 8;

  Af[0][0] = *(const float4*)(ap0);
  Af[0][1] = *(const float4*)(ap0 + 4);
  Af[1][0] = *(const float4*)(ap1);
  Af[1][1] = *(const float4*)(ap1 + 4);
  BLOAD(0, 0, 0); BLOAD(0, 1, 1); BLOAD(0, 2, 2); BLOAD(0, 3, 3);

  for (int k0b = 0; k0b < 8; ++k0b) {
    #pragma unroll
    for (int mt = 0; mt < 2; ++mt) {
      float xs[8] = {Af[mt][0].x, Af[mt][0].y, Af[mt][0].z, Af[mt][0].w,
                     Af[mt][1].x, Af[mt][1].y, Af[mt][1].z, Af[mt][1].w};
      #pragma unroll
      for (int j = 0; j < 8; ++j) {
        unsigned short h = f2bf(xs[j]);
        float r = xs[j] - bf2f(h);
        unsigned short mm = f2bf(r);
        float r2 = r - bf2f(mm);
        unsigned short ll = f2bf(r2);
        ah[mt][j] = (short)h; am[mt][j] = (short)mm; al[mt][j] = (short)ll;
      }
    }
    if (k0b < 7) {
      const int ko = (k0b + 1) * 32;
      Af[0][0] = *(const float4*)(ap0 + ko);
      Af[0][1] = *(const float4*)(ap0 + ko + 4);
      Af[1][0] = *(const float4*)(ap1 + ko);
      Af[1][1] = *(const float4*)(ap1 + ko + 4);
    }

#define GROUP(NT, S) do { \
    f32x4 c0 = acc[0][NT], c1 = acc[1][NT]; \
    c0 = __builtin_amdgcn_mfma_f32_16x16x32_bf16(ah[0], Bh[S], c0, 0, 0, 0); \
    c1 = __builtin_amdgcn_mfma_f32_16x16x32_bf16(ah[1], Bh[S], c1, 0, 0, 0); \
    c0 = __builtin_amdgcn_mfma_f32_16x16x32_bf16(ah[0], Bm[S], c0, 0, 0, 0); \
    c1 = __builtin_amdgcn_mfma_f32_16x16x32_bf16(ah[1], Bm[S], c1, 0, 0, 0); \
    c0 = __builtin_amdgcn_mfma_f32_16x16x32_bf16(am[0], Bh[S], c0, 0, 0, 0); \
    c1 = __builtin_amdgcn_mfma_f32_16x16x32_bf16(am[1], Bh[S], c1, 0, 0, 0); \
    c0 = __builtin_amdgcn_mfma_f32_16x16x32_bf16(ah[0], Bl[S], c0, 0, 0, 0); \
    c1 = __builtin_amdgcn_mfma_f32_16x16x32_bf16(ah[1], Bl[S], c1, 0, 0, 0); \
    c0 = __builtin_amdgcn_mfma_f32_16x16x32_bf16(am[0], Bm[S], c0, 0, 0, 0); \
    c1 = __builtin_amdgcn_mfma_f32_16x16x32_bf16(am[1], Bm[S], c1, 0, 0, 0); \
    c0 = __builtin_amdgcn_mfma_f32_16x16x32_bf16(al[0], Bh[S], c0, 0, 0, 0); \
    c1 = __builtin_amdgcn_mfma_f32_16x16x32_bf16(al[1], Bh[S], c1, 0, 0, 0); \
    acc[0][NT] = c0; acc[1][NT] = c1; \
  } while (0)

    GROUP(0, 0);  BLOAD(k0b, 4, 0);
    GROUP(1, 1);  BLOAD(k0b, 5, 1);
    GROUP(2, 2);  BLOAD(k0b, 6, 2);
    GROUP(3, 3);  BLOAD(k0b, 7, 3);
    GROUP(4, 0);  if (k0b < 7) BLOAD(k0b + 1, 0, 0);
    GROUP(5, 1);  if (k0b < 7) BLOAD(k0b + 1, 1, 1);
    GROUP(6, 2);  if (k0b < 7) BLOAD(k0b + 1, 2, 2);
    GROUP(7, 3);  if (k0b < 7) BLOAD(k0b + 1, 3, 3);
#undef GROUP
  }
#undef BLOAD

  // C/D layout: row = quad*4 + reg, col = lr (within each 16x16 tile)
  #pragma unroll
  for (int mt = 0; mt < 2; ++mt)
    #pragma unroll
    for (int nt = 0; nt < 8; ++nt)
      #pragma unroll
      for (int r = 0; r < 4; ++r) {
        int row = m0 + mt * 16 + quad * 4 + r;
        C[(size_t)row * DOUT_ + (nt0 + nt) * 16 + lr] = acc[mt][nt][r];
      }
}

// ---------------- z_soft: softmax + Z + squash, one block per b, 4 waves.
// logits reconstructed in-kernel: rlog + (accA+accB) * 2^-26 (exact int64 partials).
#define DSCALE     67108864.0f            // 2^26
#define DSCALE_INV 1.4901161193847656e-8f // 2^-26

__global__ __launch_bounds__(256, 4)
void z_soft(const float* __restrict__ mapped,
            const float* __restrict__ rlog,
            const long long* __restrict__ accA,
            const long long* __restrict__ accB,
            const int* __restrict__ seq_len,
            float* __restrict__ caps)
{
  const int t    = threadIdx.x;
  const int lane = t & 63;
  const int wave = t >> 6;
  const int b    = blockIdx.x;
  const int len  = seq_len[b];            // 1..200

  __shared__ float wsmT[200][8];          // weights, transposed [l][k]  (6400 B)
  __shared__ float zred[2][8][256];       // Z cross-wave reduction     (16384 B)
  __shared__ float sqred[4][8];           // squash norm partials         (128 B)

  // ---- Phase A: masked softmax; wave w owns k = 2w, 2w+1
  #pragma unroll
  for (int kk = 0; kk < 2; ++kk) {
    const int k = wave * 2 + kk;
    float v[4];
    float mx = -3.4028235e38f;
    #pragma unroll
    for (int i = 0; i < 4; ++i) {
      int l = lane + 64 * i;
      float lv = -3.4028235e38f;
      if (l < len) {
        long long a = accA[(k * L_ + l) * 8] + accB[(k * L_ + l) * 8];
        lv = rlog[k * L_ + l] + (float)a * DSCALE_INV;
      }
      v[i] = lv;
      mx = fmaxf(mx, lv);
    }
    #pragma unroll
    for (int s = 1; s < 64; s <<= 1) mx = fmaxf(mx, __shfl_xor(mx, s, 64));
    float e[4]; float sum = 0.f;
    #pragma unroll
    for (int i = 0; i < 4; ++i) {
      int l = lane + 64 * i;
      e[i] = (l < len) ? __expf(v[i] - mx) : 0.f;
      sum += e[i];
    }
    #pragma unroll
    for (int s = 1; s < 64; s <<= 1) sum += __shfl_xor(sum, s, 64);
    float inv = 1.f / sum;
    #pragma unroll
    for (int i = 0; i < 4; ++i) {
      int l = lane + 64 * i;
      if (l < L_) wsmT[l][k] = e[i] * inv;
    }
  }
  __syncthreads();

  // ---- Phase B: Z partial; wave w handles rows l == w (mod 4), all 256 channels
  f32x4 zacc[K_];
  #pragma unroll
  for (int k = 0; k < K_; ++k) zacc[k] = (f32x4){0.f, 0.f, 0.f, 0.f};

  const float* mp = mapped + (size_t)b * (L_ * DOUT_) + lane * 4;
  for (int l = wave; l < len; l += 4) {
    f32x4 m = *(const f32x4*)(mp + (size_t)l * DOUT_);
    float4 w0 = *(const float4*)&wsmT[l][0];
    float4 w1 = *(const float4*)&wsmT[l][4];
    zacc[0] += w0.x * m; zacc[1] += w0.y * m;
    zacc[2] += w0.z * m; zacc[3] += w0.w * m;
    zacc[4] += w1.x * m; zacc[5] += w1.y * m;
    zacc[6] += w1.z * m; zacc[7] += w1.w * m;
  }

  // two-stage cross-wave reduce
  if (wave >= 2) {
    #pragma unroll
    for (int k = 0; k < K_; ++k)
      *(f32x4*)&zred[wave - 2][k][lane * 4] = zacc[k];
  }
  __syncthreads();
  if (wave < 2) {
    #pragma unroll
    for (int k = 0; k < K_; ++k) {
      f32x4 r = *(const f32x4*)&zred[wave][k][lane * 4];
      r += zacc[k];
      *(f32x4*)&zred[wave][k][lane * 4] = r;
    }
  }
  __syncthreads();

  // ---- Phase C: combine + squash; thread t owns channel t
  float z[K_];
  #pragma unroll
  for (int k = 0; k < K_; ++k) z[k] = zred[0][k][t] + zred[1][k][t];

  #pragma unroll
  for (int k = 0; k < K_; ++k) {
    float s2 = z[k] * z[k];
    #pragma unroll
    for (int s = 1; s < 64; s <<= 1) s2 += __shfl_xor(s2, s, 64);
    if (lane == 0) sqred[wave][k] = s2;
  }
  __syncthreads();
  #pragma unroll
  for (int k = 0; k < K_; ++k) {
    float sq = sqred[0][k] + sqred[1][k] + sqred[2][k] + sqred[3][k];
    float scale = sq / ((1.f + sq) * sqrtf(sq + 1e-8f));
    caps[((size_t)b * K_ + k) * DOUT_ + t] = scale * z[k];
  }
}

// ---------------- delta: register-blocked over 16 b x 8 l per wave;
// epilogue adds exact int64 fixed-point partials via device atomics (102K atomics).
__global__ __launch_bounds__(256)
void delta_kernel(const float* __restrict__ mapped, const float* __restrict__ caps,
                  long long* __restrict__ accOut)
{
  const int t    = threadIdx.x;
  const int lane = t & 63;
  const int wave = t >> 6;
  const int wid  = blockIdx.x * 4 + wave;   // 0..1599
  const int lc   = wid % 25;                // l-chunk: 8 l's
  const int bc   = wid / 25;                // b-chunk: 16 b's (0..63)
  const int l0   = lc * 8;
  const int o4   = lane * 4;

  const float* cb = caps   + (size_t)(bc * 16) * (K_ * DOUT_) + o4;
  const float* mb = mapped + ((size_t)(bc * 16) * L_ + l0) * DOUT_ + o4;

  float acc[K_][8];
  #pragma unroll
  for (int k = 0; k < K_; ++k)
    #pragma unroll
    for (int ll = 0; ll < 8; ++ll) acc[k][ll] = 0.f;

  float4 cA[K_], mA[8], cB[K_], mB[8];

#define LOADC(DST, BI) do { \
    const float* _p = cb + (size_t)(BI) * (K_ * DOUT_); \
    _Pragma("unroll") \
    for (int _k = 0; _k < K_; ++_k) DST[_k] = *(const float4*)(_p + _k * DOUT_); \
  } while (0)
#define LOADM(DST, BI) do { \
    const float* _p = mb + (size_t)(BI) * (L_ * DOUT_); \
    _Pragma("unroll") \
    for (int _l = 0; _l < 8; ++_l) DST[_l] = *(const float4*)(_p + _l * DOUT_); \
  } while (0)
#define COMPUTE(CC, MM) do { \
    _Pragma("unroll") \
    for (int _k = 0; _k < K_; ++_k) \
      _Pragma("unroll") \
      for (int _l = 0; _l < 8; ++_l) \
        acc[_k][_l] += CC[_k].x * MM[_l].x + CC[_k].y * MM[_l].y \
                     + CC[_k].z * MM[_l].z + CC[_k].w * MM[_l].w; \
  } while (0)

  LOADC(cA, 0); LOADM(mA, 0);
  for (int i = 0; i < 8; ++i) {           // 2 b per iteration, double-buffered
    LOADC(cB, 2 * i + 1); LOADM(mB, 2 * i + 1);
    COMPUTE(cA, mA);
    if (i < 7) { LOADC(cA, 2 * i + 2); LOADM(mA, 2 * i + 2); }
    COMPUTE(cB, mB);
  }
#undef LOADC
#undef LOADM
#undef COMPUTE

  // lane-reduce each (k,ll) over the 64 lanes (256 channels); lane k*8+ll keeps it
  float out = 0.f;
  #pragma unroll
  for (int k = 0; k < K_; ++k)
    #pragma unroll
    for (int ll = 0; ll < 8; ++ll) {
      float v = acc[k][ll];
      v += __shfl_xor(v, 1, 64);
      v += __shfl_xor(v, 2, 64);
      v += __shfl_xor(v, 4, 64);
      v += __shfl_xor(v, 8, 64);
      v += __shfl_xor(v, 16, 64);
      v += __shfl_xor(v, 32, 64);
      if (lane == k * 8 + ll) out = v;
    }
  // lane owns (k = lane>>3, l = l0 + (lane&7)); exact fixed-point accumulate
  long long q = llrintf(out * DSCALE);
  atomicAdd((unsigned long long*)&accOut[((size_t)(lane >> 3) * L_ + l0 + (lane & 7)) * 8],
            (unsigned long long)q);
}

// ---------------- zero the three int64 accumulator buffers (38400 entries)
__global__ __launch_bounds__(256)
void init_acc(long long* __restrict__ a)
{
  int i = blockIdx.x * 256 + threadIdx.x;
  a[i] = 0;
}

extern "C" void kernel_launch(void* const* d_in, const int* in_sizes, int n_in,
                              void* d_out, int out_size, void* d_ws, size_t ws_size,
                              hipStream_t stream)
{
  const float* behav = (const float*)d_in[0];
  const int*   slen  = (const int*)d_in[1];
  const float* rlog  = (const float*)d_in[2];
  const float* W     = (const float*)d_in[3];
  float* caps = (float*)d_out;

  char* ws = (char*)d_ws;
  // acc buffers: 1600 counters padded to one 64B line each -> 102400 B apiece
  long long* z0   = (long long*)ws;                      // always-zero
  long long* acc0 = (long long*)(ws + 102400);
  long long* acc1 = (long long*)(ws + 204800);           // ends 307200
  unsigned short* Wh = (unsigned short*)(ws + 327680);   // 128 KiB each
  unsigned short* Wm = (unsigned short*)(ws + 458752);
  unsigned short* Wl = (unsigned short*)(ws + 589824);   // ends 720896 < 1 MiB
  float* mapped   = (float*)(ws + (1 << 20));            // 200 MiB fp32

  init_acc<<<dim3(150), 256, 0, stream>>>((long long*)ws);   // zeroes z0,acc0,acc1
  wt_prep<<<dim3(256), 256, 0, stream>>>(W, Wh, Wm, Wl);
  gemm_mapped<<<dim3(3200), 256, 0, stream>>>(behav, Wh, Wm, Wl, mapped);

  // it0: logits = rlog               -> caps, then delta -> acc0
  z_soft<<<dim3(B_), 256, 0, stream>>>(mapped, rlog, z0,   z0,   slen, caps);
  delta_kernel<<<dim3(400), 256, 0, stream>>>(mapped, caps, acc0);
  // it1: logits = rlog + acc0        -> caps, then delta -> acc1
  z_soft<<<dim3(B_), 256, 0, stream>>>(mapped, rlog, acc0, z0,   slen, caps);
  delta_kernel<<<dim3(400), 256, 0, stream>>>(mapped, caps, acc1);
  // it2: logits = rlog + acc0 + acc1 -> final caps
  z_soft<<<dim3(B_), 256, 0, stream>>>(mapped, rlog, acc0, acc1, slen, caps);
}

// Round 4
// 606.122 us; speedup vs baseline: 1.1806x; 1.1806x over previous
//
#include <hip/hip_runtime.h>
#include <cstdint>
#include <cstddef>

#define B_    1024
#define L_    200
#define DIN_  256
#define DOUT_ 256
#define K_    8
#define M_    (B_ * L_)   // 204800

typedef __attribute__((ext_vector_type(8))) short bf16x8;
typedef __attribute__((ext_vector_type(4))) float f32x4;

__device__ __forceinline__ float bf2f(unsigned short u) {
  union { unsigned int i; float f; } w; w.i = ((unsigned int)u) << 16; return w.f;
}
__device__ __forceinline__ unsigned short f2bf(float f) {
  union { float f; unsigned int i; } w; w.f = f;
  unsigned int x = w.i;
  return (unsigned short)((x + 0x7fffu + ((x >> 16) & 1u)) >> 16);
}

// ---------------- kernel 0: split W into bf16 hi/mid/lo in MFMA FRAGMENT ORDER.
__global__ __launch_bounds__(256)
void wt_prep(const float* __restrict__ W, unsigned short* __restrict__ Wh,
             unsigned short* __restrict__ Wm, unsigned short* __restrict__ Wl)
{
  const int k = blockIdx.x;    // 256
  const int n = threadIdx.x;   // 256
  float x = W[k * DOUT_ + n];
  unsigned short h = f2bf(x);
  float r = x - bf2f(h);
  unsigned short m = f2bf(r);
  float r2 = r - bf2f(m);
  unsigned short l = f2bf(r2);
  const int k0b = k >> 5, quad = (k >> 3) & 3, j = k & 7;
  const int nt = n >> 4, lr = n & 15;
  const size_t idx = ((((size_t)k0b * 16 + nt) * 64) + (quad * 16 + lr)) * 8 + j;
  Wh[idx] = h;
  Wm[idx] = m;
  Wl[idx] = l;
}

// ---------------- kernel 1: mapped = A @ W via bf16x3-split MFMA.
// REVERTED to the R2 version (208 us measured): wave = 32x256, acc[2][16],
// 4-slot rolling B prefetch, 16-group body for latency amortization.
__global__ __launch_bounds__(256, 2)
void gemm_mapped(const float* __restrict__ A,
                 const unsigned short* __restrict__ Wh,
                 const unsigned short* __restrict__ Wm,
                 const unsigned short* __restrict__ Wl,
                 float* __restrict__ C)
{
  const int t    = threadIdx.x;
  const int wave = t >> 6;
  const int lane = t & 63;
  const int quad = lane >> 4;
  const int lr   = lane & 15;
  const int m0   = blockIdx.x * 128 + wave * 32;

  f32x4 acc[2][16];
  #pragma unroll
  for (int mt = 0; mt < 2; ++mt)
    #pragma unroll
    for (int nt = 0; nt < 16; ++nt)
      acc[mt][nt] = (f32x4){0.f, 0.f, 0.f, 0.f};

  bf16x8 Bh[4], Bm[4], Bl[4];
  bf16x8 ah[2], am[2], al[2];
  float4 Af[2][2];

#define BLOAD(K0B, NT, S) do { \
    const size_t _off = (((size_t)(K0B) * 16 + (NT)) * 64 + lane) * 8; \
    Bh[S] = *(const bf16x8*)(Wh + _off); \
    Bm[S] = *(const bf16x8*)(Wm + _off); \
    Bl[S] = *(const bf16x8*)(Wl + _off); \
  } while (0)

  const float* ap0 = A + (size_t)(m0 + lr) * DIN_ + quad * 8;
  const float* ap1 = A + (size_t)(m0 + 16 + lr) * DIN_ + quad * 8;

  Af[0][0] = *(const float4*)(ap0);
  Af[0][1] = *(const float4*)(ap0 + 4);
  Af[1][0] = *(const float4*)(ap1);
  Af[1][1] = *(const float4*)(ap1 + 4);
  BLOAD(0, 0, 0); BLOAD(0, 1, 1); BLOAD(0, 2, 2); BLOAD(0, 3, 3);

  for (int k0b = 0; k0b < 8; ++k0b) {
    #pragma unroll
    for (int mt = 0; mt < 2; ++mt) {
      float xs[8] = {Af[mt][0].x, Af[mt][0].y, Af[mt][0].z, Af[mt][0].w,
                     Af[mt][1].x, Af[mt][1].y, Af[mt][1].z, Af[mt][1].w};
      #pragma unroll
      for (int j = 0; j < 8; ++j) {
        unsigned short h = f2bf(xs[j]);
        float r = xs[j] - bf2f(h);
        unsigned short mm = f2bf(r);
        float r2 = r - bf2f(mm);
        unsigned short ll = f2bf(r2);
        ah[mt][j] = (short)h; am[mt][j] = (short)mm; al[mt][j] = (short)ll;
      }
    }
    if (k0b < 7) {
      const int ko = (k0b + 1) * 32;
      Af[0][0] = *(const float4*)(ap0 + ko);
      Af[0][1] = *(const float4*)(ap0 + ko + 4);
      Af[1][0] = *(const float4*)(ap1 + ko);
      Af[1][1] = *(const float4*)(ap1 + ko + 4);
    }

#define GROUP(NT, S) do { \
    f32x4 c0 = acc[0][NT], c1 = acc[1][NT]; \
    c0 = __builtin_amdgcn_mfma_f32_16x16x32_bf16(ah[0], Bh[S], c0, 0, 0, 0); \
    c1 = __builtin_amdgcn_mfma_f32_16x16x32_bf16(ah[1], Bh[S], c1, 0, 0, 0); \
    c0 = __builtin_amdgcn_mfma_f32_16x16x32_bf16(ah[0], Bm[S], c0, 0, 0, 0); \
    c1 = __builtin_amdgcn_mfma_f32_16x16x32_bf16(ah[1], Bm[S], c1, 0, 0, 0); \
    c0 = __builtin_amdgcn_mfma_f32_16x16x32_bf16(am[0], Bh[S], c0, 0, 0, 0); \
    c1 = __builtin_amdgcn_mfma_f32_16x16x32_bf16(am[1], Bh[S], c1, 0, 0, 0); \
    c0 = __builtin_amdgcn_mfma_f32_16x16x32_bf16(ah[0], Bl[S], c0, 0, 0, 0); \
    c1 = __builtin_amdgcn_mfma_f32_16x16x32_bf16(ah[1], Bl[S], c1, 0, 0, 0); \
    c0 = __builtin_amdgcn_mfma_f32_16x16x32_bf16(am[0], Bm[S], c0, 0, 0, 0); \
    c1 = __builtin_amdgcn_mfma_f32_16x16x32_bf16(am[1], Bm[S], c1, 0, 0, 0); \
    c0 = __builtin_amdgcn_mfma_f32_16x16x32_bf16(al[0], Bh[S], c0, 0, 0, 0); \
    c1 = __builtin_amdgcn_mfma_f32_16x16x32_bf16(al[1], Bh[S], c1, 0, 0, 0); \
    acc[0][NT] = c0; acc[1][NT] = c1; \
  } while (0)

    GROUP(0, 0);  BLOAD(k0b, 4, 0);
    GROUP(1, 1);  BLOAD(k0b, 5, 1);
    GROUP(2, 2);  BLOAD(k0b, 6, 2);
    GROUP(3, 3);  BLOAD(k0b, 7, 3);
    GROUP(4, 0);  BLOAD(k0b, 8, 0);
    GROUP(5, 1);  BLOAD(k0b, 9, 1);
    GROUP(6, 2);  BLOAD(k0b, 10, 2);
    GROUP(7, 3);  BLOAD(k0b, 11, 3);
    GROUP(8, 0);  BLOAD(k0b, 12, 0);
    GROUP(9, 1);  BLOAD(k0b, 13, 1);
    GROUP(10, 2); BLOAD(k0b, 14, 2);
    GROUP(11, 3); BLOAD(k0b, 15, 3);
    GROUP(12, 0);
    GROUP(13, 1);
    GROUP(14, 2);
    GROUP(15, 3);
    if (k0b < 7) {
      BLOAD(k0b + 1, 0, 0); BLOAD(k0b + 1, 1, 1);
      BLOAD(k0b + 1, 2, 2); BLOAD(k0b + 1, 3, 3);
    }
#undef GROUP
  }
#undef BLOAD

  // C/D layout: row = quad*4 + reg, col = lr (within each 16x16 tile)
  #pragma unroll
  for (int mt = 0; mt < 2; ++mt)
    #pragma unroll
    for (int nt = 0; nt < 16; ++nt)
      #pragma unroll
      for (int r = 0; r < 4; ++r) {
        int row = m0 + mt * 16 + quad * 4 + r;
        C[(size_t)row * DOUT_ + nt * 16 + lr] = acc[mt][nt][r];
      }
}

// ---------------- z_soft: softmax + Z + squash, one block per b, 4 waves.
// logits reconstructed in-kernel: rlog + (accA+accB) * 2^-26 (exact int64 partials).
#define DSCALE     67108864.0f            // 2^26
#define DSCALE_INV 1.4901161193847656e-8f // 2^-26

__global__ __launch_bounds__(256, 4)
void z_soft(const float* __restrict__ mapped,
            const float* __restrict__ rlog,
            const long long* __restrict__ accA,
            const long long* __restrict__ accB,
            const int* __restrict__ seq_len,
            float* __restrict__ caps)
{
  const int t    = threadIdx.x;
  const int lane = t & 63;
  const int wave = t >> 6;
  const int b    = blockIdx.x;
  const int len  = seq_len[b];            // 1..200

  __shared__ float wsmT[200][8];          // weights, transposed [l][k]  (6400 B)
  __shared__ float zred[2][8][256];       // Z cross-wave reduction     (16384 B)
  __shared__ float sqred[4][8];           // squash norm partials         (128 B)

  // ---- Phase A: masked softmax; wave w owns k = 2w, 2w+1
  #pragma unroll
  for (int kk = 0; kk < 2; ++kk) {
    const int k = wave * 2 + kk;
    float v[4];
    float mx = -3.4028235e38f;
    #pragma unroll
    for (int i = 0; i < 4; ++i) {
      int l = lane + 64 * i;
      float lv = -3.4028235e38f;
      if (l < len) {
        long long a = accA[(k * L_ + l) * 8] + accB[(k * L_ + l) * 8];
        lv = rlog[k * L_ + l] + (float)a * DSCALE_INV;
      }
      v[i] = lv;
      mx = fmaxf(mx, lv);
    }
    #pragma unroll
    for (int s = 1; s < 64; s <<= 1) mx = fmaxf(mx, __shfl_xor(mx, s, 64));
    float e[4]; float sum = 0.f;
    #pragma unroll
    for (int i = 0; i < 4; ++i) {
      int l = lane + 64 * i;
      e[i] = (l < len) ? __expf(v[i] - mx) : 0.f;
      sum += e[i];
    }
    #pragma unroll
    for (int s = 1; s < 64; s <<= 1) sum += __shfl_xor(sum, s, 64);
    float inv = 1.f / sum;
    #pragma unroll
    for (int i = 0; i < 4; ++i) {
      int l = lane + 64 * i;
      if (l < L_) wsmT[l][k] = e[i] * inv;
    }
  }
  __syncthreads();

  // ---- Phase B: Z partial; wave w handles rows l == w (mod 4), all 256 channels
  f32x4 zacc[K_];
  #pragma unroll
  for (int k = 0; k < K_; ++k) zacc[k] = (f32x4){0.f, 0.f, 0.f, 0.f};

  const float* mp = mapped + (size_t)b * (L_ * DOUT_) + lane * 4;
  for (int l = wave; l < len; l += 4) {
    f32x4 m = *(const f32x4*)(mp + (size_t)l * DOUT_);
    float4 w0 = *(const float4*)&wsmT[l][0];
    float4 w1 = *(const float4*)&wsmT[l][4];
    zacc[0] += w0.x * m; zacc[1] += w0.y * m;
    zacc[2] += w0.z * m; zacc[3] += w0.w * m;
    zacc[4] += w1.x * m; zacc[5] += w1.y * m;
    zacc[6] += w1.z * m; zacc[7] += w1.w * m;
  }

  // two-stage cross-wave reduce
  if (wave >= 2) {
    #pragma unroll
    for (int k = 0; k < K_; ++k)
      *(f32x4*)&zred[wave - 2][k][lane * 4] = zacc[k];
  }
  __syncthreads();
  if (wave < 2) {
    #pragma unroll
    for (int k = 0; k < K_; ++k) {
      f32x4 r = *(const f32x4*)&zred[wave][k][lane * 4];
      r += zacc[k];
      *(f32x4*)&zred[wave][k][lane * 4] = r;
    }
  }
  __syncthreads();

  // ---- Phase C: combine + squash; thread t owns channel t
  float z[K_];
  #pragma unroll
  for (int k = 0; k < K_; ++k) z[k] = zred[0][k][t] + zred[1][k][t];

  #pragma unroll
  for (int k = 0; k < K_; ++k) {
    float s2 = z[k] * z[k];
    #pragma unroll
    for (int s = 1; s < 64; s <<= 1) s2 += __shfl_xor(s2, s, 64);
    if (lane == 0) sqred[wave][k] = s2;
  }
  __syncthreads();
  #pragma unroll
  for (int k = 0; k < K_; ++k) {
    float sq = sqred[0][k] + sqred[1][k] + sqred[2][k] + sqred[3][k];
    float scale = sq / ((1.f + sq) * sqrtf(sq + 1e-8f));
    caps[((size_t)b * K_ + k) * DOUT_ + t] = scale * z[k];
  }
}

// ---------------- delta: register-blocked over 16 b x 4 l per wave (was 8 l).
// Grid 800 -> ~3.1 waves/SIMD for latency hiding. Per-(k,l) partials are the
// same 16-b sums as before -> quantized int64 values bit-identical.
__global__ __launch_bounds__(256)
void delta_kernel(const float* __restrict__ mapped, const float* __restrict__ caps,
                  long long* __restrict__ accOut)
{
  const int t    = threadIdx.x;
  const int lane = t & 63;
  const int wave = t >> 6;
  const int wid  = blockIdx.x * 4 + wave;   // 0..3199
  const int lc   = wid % 50;                // l-chunk: 4 l's
  const int bc   = wid / 50;                // b-chunk: 16 b's (0..63)
  const int l0   = lc * 4;
  const int o4   = lane * 4;

  const float* cb = caps   + (size_t)(bc * 16) * (K_ * DOUT_) + o4;
  const float* mb = mapped + ((size_t)(bc * 16) * L_ + l0) * DOUT_ + o4;

  float acc[K_][4];
  #pragma unroll
  for (int k = 0; k < K_; ++k)
    #pragma unroll
    for (int ll = 0; ll < 4; ++ll) acc[k][ll] = 0.f;

  float4 cA[K_], mA[4], cB[K_], mB[4];

#define LOADC(DST, BI) do { \
    const float* _p = cb + (size_t)(BI) * (K_ * DOUT_); \
    _Pragma("unroll") \
    for (int _k = 0; _k < K_; ++_k) DST[_k] = *(const float4*)(_p + _k * DOUT_); \
  } while (0)
#define LOADM(DST, BI) do { \
    const float* _p = mb + (size_t)(BI) * (L_ * DOUT_); \
    _Pragma("unroll") \
    for (int _l = 0; _l < 4; ++_l) DST[_l] = *(const float4*)(_p + _l * DOUT_); \
  } while (0)
#define COMPUTE(CC, MM) do { \
    _Pragma("unroll") \
    for (int _k = 0; _k < K_; ++_k) \
      _Pragma("unroll") \
      for (int _l = 0; _l < 4; ++_l) \
        acc[_k][_l] += CC[_k].x * MM[_l].x + CC[_k].y * MM[_l].y \
                     + CC[_k].z * MM[_l].z + CC[_k].w * MM[_l].w; \
  } while (0)

  LOADC(cA, 0); LOADM(mA, 0);
  for (int i = 0; i < 8; ++i) {           // 2 b per iteration, double-buffered
    LOADC(cB, 2 * i + 1); LOADM(mB, 2 * i + 1);
    COMPUTE(cA, mA);
    if (i < 7) { LOADC(cA, 2 * i + 2); LOADM(mA, 2 * i + 2); }
    COMPUTE(cB, mB);
  }
#undef LOADC
#undef LOADM
#undef COMPUTE

  // lane-reduce each (k,ll) over the 64 lanes (256 channels); lane k*4+ll keeps it
  float out = 0.f;
  #pragma unroll
  for (int k = 0; k < K_; ++k)
    #pragma unroll
    for (int ll = 0; ll < 4; ++ll) {
      float v = acc[k][ll];
      v += __shfl_xor(v, 1, 64);
      v += __shfl_xor(v, 2, 64);
      v += __shfl_xor(v, 4, 64);
      v += __shfl_xor(v, 8, 64);
      v += __shfl_xor(v, 16, 64);
      v += __shfl_xor(v, 32, 64);
      if (lane == k * 4 + ll) out = v;
    }
  // lanes 0..31 own (k = lane>>2, l = l0 + (lane&3)); exact fixed-point accumulate
  if (lane < 32) {
    long long q = llrintf(out * DSCALE);
    atomicAdd((unsigned long long*)&accOut[((size_t)(lane >> 2) * L_ + l0 + (lane & 3)) * 8],
              (unsigned long long)q);
  }
}

// ---------------- zero the three int64 accumulator buffers (38400 entries)
__global__ __launch_bounds__(256)
void init_acc(long long* __restrict__ a)
{
  int i = blockIdx.x * 256 + threadIdx.x;
  a[i] = 0;
}

extern "C" void kernel_launch(void* const* d_in, const int* in_sizes, int n_in,
                              void* d_out, int out_size, void* d_ws, size_t ws_size,
                              hipStream_t stream)
{
  const float* behav = (const float*)d_in[0];
  const int*   slen  = (const int*)d_in[1];
  const float* rlog  = (const float*)d_in[2];
  const float* W     = (const float*)d_in[3];
  float* caps = (float*)d_out;

  char* ws = (char*)d_ws;
  // acc buffers: 1600 counters padded to one 64B line each -> 102400 B apiece
  long long* z0   = (long long*)ws;                      // always-zero
  long long* acc0 = (long long*)(ws + 102400);
  long long* acc1 = (long long*)(ws + 204800);           // ends 307200
  unsigned short* Wh = (unsigned short*)(ws + 327680);   // 128 KiB each
  unsigned short* Wm = (unsigned short*)(ws + 458752);
  unsigned short* Wl = (unsigned short*)(ws + 589824);   // ends 720896 < 1 MiB
  float* mapped   = (float*)(ws + (1 << 20));            // 200 MiB fp32

  init_acc<<<dim3(150), 256, 0, stream>>>((long long*)ws);   // zeroes z0,acc0,acc1
  wt_prep<<<dim3(256), 256, 0, stream>>>(W, Wh, Wm, Wl);
  gemm_mapped<<<dim3(1600), 256, 0, stream>>>(behav, Wh, Wm, Wl, mapped);

  // it0: logits = rlog               -> caps, then delta -> acc0
  z_soft<<<dim3(B_), 256, 0, stream>>>(mapped, rlog, z0,   z0,   slen, caps);
  delta_kernel<<<dim3(800), 256, 0, stream>>>(mapped, caps, acc0);
  // it1: logits = rlog + acc0        -> caps, then delta -> acc1
  z_soft<<<dim3(B_), 256, 0, stream>>>(mapped, rlog, acc0, z0,   slen, caps);
  delta_kernel<<<dim3(800), 256, 0, stream>>>(mapped, caps, acc1);
  // it2: logits = rlog + acc0 + acc1 -> final caps
  z_soft<<<dim3(B_), 256, 0, stream>>>(mapped, rlog, acc0, acc1, slen, caps);
}

// Round 5
// 578.093 us; speedup vs baseline: 1.2379x; 1.0485x over previous
//
#include <hip/hip_runtime.h>
#include <cstdint>
#include <cstddef>

#define B_    1024
#define L_    200
#define DIN_  256
#define DOUT_ 256
#define K_    8
#define M_    (B_ * L_)   // 204800

typedef __attribute__((ext_vector_type(8))) short bf16x8;
typedef __attribute__((ext_vector_type(4))) float f32x4;

__device__ __forceinline__ float bf2f(unsigned short u) {
  union { unsigned int i; float f; } w; w.i = ((unsigned int)u) << 16; return w.f;
}
__device__ __forceinline__ unsigned short f2bf(float f) {
  union { float f; unsigned int i; } w; w.f = f;
  unsigned int x = w.i;
  return (unsigned short)((x + 0x7fffu + ((x >> 16) & 1u)) >> 16);
}

// async 16B global -> LDS copy (wave-uniform LDS base + lane*16 pattern)
__device__ __forceinline__ void gload16(const void* g, void* l) {
  __builtin_amdgcn_global_load_lds(
      (const __attribute__((address_space(1))) unsigned int*)g,
      (__attribute__((address_space(3))) unsigned int*)l, 16, 0, 0);
}

// ---------------- kernel 0: split W into bf16 hi/mid/lo in MFMA FRAGMENT ORDER.
__global__ __launch_bounds__(256)
void wt_prep(const float* __restrict__ W, unsigned short* __restrict__ Wh,
             unsigned short* __restrict__ Wm, unsigned short* __restrict__ Wl)
{
  const int k = blockIdx.x;    // 256
  const int n = threadIdx.x;   // 256
  float x = W[k * DOUT_ + n];
  unsigned short h = f2bf(x);
  float r = x - bf2f(h);
  unsigned short m = f2bf(r);
  float r2 = r - bf2f(m);
  unsigned short l = f2bf(r2);
  const int k0b = k >> 5, quad = (k >> 3) & 3, j = k & 7;
  const int nt = n >> 4, lr = n & 15;
  const size_t idx = ((((size_t)k0b * 16 + nt) * 64) + (quad * 16 + lr)) * 8 + j;
  Wh[idx] = h;
  Wm[idx] = m;
  Wl[idx] = l;
}

// ---------------- kernel 1: mapped = A @ W via bf16x3-split MFMA.
// R5: m97-style LDS staging of B. Block = 64 rows x 256 cols, 4 waves
// (wave&1 -> M-sub, wave>>1 -> N-half; wave tile 32x128, acc[2][8]=64 regs).
// Per k0b: stage 48 KB (Wh/Wm/Wl slice) via global_load_lds, barrier, compute
// from LDS. 48 KB LDS + <=170 regs -> 3 blocks/CU, 3 waves/SIMD; cross-block
// overlap hides the stage latency. Math order per acc element unchanged ->
// bit-identical C vs R2/R4.
__global__ __launch_bounds__(256, 3)
void gemm_mapped(const float* __restrict__ A,
                 const unsigned short* __restrict__ Wh,
                 const unsigned short* __restrict__ Wm,
                 const unsigned short* __restrict__ Wl,
                 float* __restrict__ C)
{
  const int t    = threadIdx.x;
  const int wave = t >> 6;
  const int lane = t & 63;
  const int quad = lane >> 4;
  const int lr   = lane & 15;
  const int m0   = blockIdx.x * 64 + (wave & 1) * 32;
  const int nt0  = (wave >> 1) * 8;     // N-half: fragments nt0..nt0+7

  // 3 buffers (h/m/l) x 16 nt x 64 lanes x 8 shorts = 49152 B
  __shared__ unsigned short ldsB[3 * 16 * 64 * 8];

  f32x4 acc[2][8];
  #pragma unroll
  for (int mt = 0; mt < 2; ++mt)
    #pragma unroll
    for (int nt = 0; nt < 8; ++nt)
      acc[mt][nt] = (f32x4){0.f, 0.f, 0.f, 0.f};

  bf16x8 ah[2], am[2], al[2];
  float4 Af[2][2];

  const float* ap0 = A + (size_t)(m0 + lr) * DIN_ + quad * 8;
  const float* ap1 = A + (size_t)(m0 + 16 + lr) * DIN_ + quad * 8;

  // stage one k0b slice (16 KB per buffer): 4 rounds x 3 buffers per thread
#define STAGE(K0B) do { \
    const size_t _k = (size_t)(K0B) * 8192; \
    _Pragma("unroll") \
    for (int _r = 0; _r < 4; ++_r) { \
      gload16(Wh + _k + _r * 2048 + t * 8, ldsB +         _r * 2048 + t * 8); \
      gload16(Wm + _k + _r * 2048 + t * 8, ldsB +  8192 + _r * 2048 + t * 8); \
      gload16(Wl + _k + _r * 2048 + t * 8, ldsB + 16384 + _r * 2048 + t * 8); \
    } \
  } while (0)

  // prologue: A raw for k0b=0; stage B k0b=0
  Af[0][0] = *(const float4*)(ap0);
  Af[0][1] = *(const float4*)(ap0 + 4);
  Af[1][0] = *(const float4*)(ap1);
  Af[1][1] = *(const float4*)(ap1 + 4);
  STAGE(0);
  asm volatile("s_waitcnt vmcnt(0)" ::: "memory");
  __syncthreads();

  for (int k0b = 0; k0b < 8; ++k0b) {
    // convert prefetched A to bf16x3 fragments
    #pragma unroll
    for (int mt = 0; mt < 2; ++mt) {
      float xs[8] = {Af[mt][0].x, Af[mt][0].y, Af[mt][0].z, Af[mt][0].w,
                     Af[mt][1].x, Af[mt][1].y, Af[mt][1].z, Af[mt][1].w};
      #pragma unroll
      for (int j = 0; j < 8; ++j) {
        unsigned short h = f2bf(xs[j]);
        float r = xs[j] - bf2f(h);
        unsigned short mm = f2bf(r);
        float r2 = r - bf2f(mm);
        unsigned short ll = f2bf(r2);
        ah[mt][j] = (short)h; am[mt][j] = (short)mm; al[mt][j] = (short)ll;
      }
    }
    // issue next k0's A raw loads (drained by the staging vmcnt(0) below)
    if (k0b < 7) {
      const int ko = (k0b + 1) * 32;
      Af[0][0] = *(const float4*)(ap0 + ko);
      Af[0][1] = *(const float4*)(ap0 + ko + 4);
      Af[1][0] = *(const float4*)(ap1 + ko);
      Af[1][1] = *(const float4*)(ap1 + ko + 4);
    }

#define GROUP(NT) do { \
    const unsigned short* _lb = ldsB + (size_t)((nt0 + (NT)) * 64 + lane) * 8; \
    bf16x8 Bh_ = *(const bf16x8*)(_lb); \
    bf16x8 Bm_ = *(const bf16x8*)(_lb + 8192); \
    bf16x8 Bl_ = *(const bf16x8*)(_lb + 16384); \
    f32x4 c0 = acc[0][NT], c1 = acc[1][NT]; \
    c0 = __builtin_amdgcn_mfma_f32_16x16x32_bf16(ah[0], Bh_, c0, 0, 0, 0); \
    c1 = __builtin_amdgcn_mfma_f32_16x16x32_bf16(ah[1], Bh_, c1, 0, 0, 0); \
    c0 = __builtin_amdgcn_mfma_f32_16x16x32_bf16(ah[0], Bm_, c0, 0, 0, 0); \
    c1 = __builtin_amdgcn_mfma_f32_16x16x32_bf16(ah[1], Bm_, c1, 0, 0, 0); \
    c0 = __builtin_amdgcn_mfma_f32_16x16x32_bf16(am[0], Bh_, c0, 0, 0, 0); \
    c1 = __builtin_amdgcn_mfma_f32_16x16x32_bf16(am[1], Bh_, c1, 0, 0, 0); \
    c0 = __builtin_amdgcn_mfma_f32_16x16x32_bf16(ah[0], Bl_, c0, 0, 0, 0); \
    c1 = __builtin_amdgcn_mfma_f32_16x16x32_bf16(ah[1], Bl_, c1, 0, 0, 0); \
    c0 = __builtin_amdgcn_mfma_f32_16x16x32_bf16(am[0], Bm_, c0, 0, 0, 0); \
    c1 = __builtin_amdgcn_mfma_f32_16x16x32_bf16(am[1], Bm_, c1, 0, 0, 0); \
    c0 = __builtin_amdgcn_mfma_f32_16x16x32_bf16(al[0], Bh_, c0, 0, 0, 0); \
    c1 = __builtin_amdgcn_mfma_f32_16x16x32_bf16(al[1], Bh_, c1, 0, 0, 0); \
    acc[0][NT] = c0; acc[1][NT] = c1; \
  } while (0)

    GROUP(0); GROUP(1); GROUP(2); GROUP(3);
    GROUP(4); GROUP(5); GROUP(6); GROUP(7);
#undef GROUP

    __syncthreads();                      // all waves done reading this slice
    if (k0b < 7) {
      STAGE(k0b + 1);
      asm volatile("s_waitcnt vmcnt(0)" ::: "memory");
      __syncthreads();                    // staged slice visible to all
    }
  }
#undef STAGE

  // C/D layout: row = quad*4 + reg, col = lr (within each 16x16 tile)
  #pragma unroll
  for (int mt = 0; mt < 2; ++mt)
    #pragma unroll
    for (int nt = 0; nt < 8; ++nt)
      #pragma unroll
      for (int r = 0; r < 4; ++r) {
        int row = m0 + mt * 16 + quad * 4 + r;
        C[(size_t)row * DOUT_ + (nt0 + nt) * 16 + lr] = acc[mt][nt][r];
      }
}

// ---------------- z_soft: softmax + Z + squash, one block per b, 4 waves.
// logits reconstructed in-kernel: rlog + (accA+accB) * 2^-26 (exact int64 partials).
#define DSCALE     67108864.0f            // 2^26
#define DSCALE_INV 1.4901161193847656e-8f // 2^-26

__global__ __launch_bounds__(256, 4)
void z_soft(const float* __restrict__ mapped,
            const float* __restrict__ rlog,
            const long long* __restrict__ accA,
            const long long* __restrict__ accB,
            const int* __restrict__ seq_len,
            float* __restrict__ caps)
{
  const int t    = threadIdx.x;
  const int lane = t & 63;
  const int wave = t >> 6;
  const int b    = blockIdx.x;
  const int len  = seq_len[b];            // 1..200

  __shared__ float wsmT[200][8];          // weights, transposed [l][k]  (6400 B)
  __shared__ float zred[2][8][256];       // Z cross-wave reduction     (16384 B)
  __shared__ float sqred[4][8];           // squash norm partials         (128 B)

  // ---- Phase A: masked softmax; wave w owns k = 2w, 2w+1
  #pragma unroll
  for (int kk = 0; kk < 2; ++kk) {
    const int k = wave * 2 + kk;
    float v[4];
    float mx = -3.4028235e38f;
    #pragma unroll
    for (int i = 0; i < 4; ++i) {
      int l = lane + 64 * i;
      float lv = -3.4028235e38f;
      if (l < len) {
        long long a = accA[(k * L_ + l) * 8] + accB[(k * L_ + l) * 8];
        lv = rlog[k * L_ + l] + (float)a * DSCALE_INV;
      }
      v[i] = lv;
      mx = fmaxf(mx, lv);
    }
    #pragma unroll
    for (int s = 1; s < 64; s <<= 1) mx = fmaxf(mx, __shfl_xor(mx, s, 64));
    float e[4]; float sum = 0.f;
    #pragma unroll
    for (int i = 0; i < 4; ++i) {
      int l = lane + 64 * i;
      e[i] = (l < len) ? __expf(v[i] - mx) : 0.f;
      sum += e[i];
    }
    #pragma unroll
    for (int s = 1; s < 64; s <<= 1) sum += __shfl_xor(sum, s, 64);
    float inv = 1.f / sum;
    #pragma unroll
    for (int i = 0; i < 4; ++i) {
      int l = lane + 64 * i;
      if (l < L_) wsmT[l][k] = e[i] * inv;
    }
  }
  __syncthreads();

  // ---- Phase B: Z partial; wave w handles rows l == w (mod 4), all 256 channels
  f32x4 zacc[K_];
  #pragma unroll
  for (int k = 0; k < K_; ++k) zacc[k] = (f32x4){0.f, 0.f, 0.f, 0.f};

  const float* mp = mapped + (size_t)b * (L_ * DOUT_) + lane * 4;
  for (int l = wave; l < len; l += 4) {
    f32x4 m = *(const f32x4*)(mp + (size_t)l * DOUT_);
    float4 w0 = *(const float4*)&wsmT[l][0];
    float4 w1 = *(const float4*)&wsmT[l][4];
    zacc[0] += w0.x * m; zacc[1] += w0.y * m;
    zacc[2] += w0.z * m; zacc[3] += w0.w * m;
    zacc[4] += w1.x * m; zacc[5] += w1.y * m;
    zacc[6] += w1.z * m; zacc[7] += w1.w * m;
  }

  // two-stage cross-wave reduce
  if (wave >= 2) {
    #pragma unroll
    for (int k = 0; k < K_; ++k)
      *(f32x4*)&zred[wave - 2][k][lane * 4] = zacc[k];
  }
  __syncthreads();
  if (wave < 2) {
    #pragma unroll
    for (int k = 0; k < K_; ++k) {
      f32x4 r = *(const f32x4*)&zred[wave][k][lane * 4];
      r += zacc[k];
      *(f32x4*)&zred[wave][k][lane * 4] = r;
    }
  }
  __syncthreads();

  // ---- Phase C: combine + squash; thread t owns channel t
  float z[K_];
  #pragma unroll
  for (int k = 0; k < K_; ++k) z[k] = zred[0][k][t] + zred[1][k][t];

  #pragma unroll
  for (int k = 0; k < K_; ++k) {
    float s2 = z[k] * z[k];
    #pragma unroll
    for (int s = 1; s < 64; s <<= 1) s2 += __shfl_xor(s2, s, 64);
    if (lane == 0) sqred[wave][k] = s2;
  }
  __syncthreads();
  #pragma unroll
  for (int k = 0; k < K_; ++k) {
    float sq = sqred[0][k] + sqred[1][k] + sqred[2][k] + sqred[3][k];
    float scale = sq / ((1.f + sq) * sqrtf(sq + 1e-8f));
    caps[((size_t)b * K_ + k) * DOUT_ + t] = scale * z[k];
  }
}

// ---------------- delta: register-blocked over 16 b x 4 l per wave.
// Grid 800 -> ~3.1 waves/SIMD. Per-(k,l) partials are 16-b sums -> int64 exact.
__global__ __launch_bounds__(256)
void delta_kernel(const float* __restrict__ mapped, const float* __restrict__ caps,
                  long long* __restrict__ accOut)
{
  const int t    = threadIdx.x;
  const int lane = t & 63;
  const int wave = t >> 6;
  const int wid  = blockIdx.x * 4 + wave;   // 0..3199
  const int lc   = wid % 50;                // l-chunk: 4 l's
  const int bc   = wid / 50;                // b-chunk: 16 b's (0..63)
  const int l0   = lc * 4;
  const int o4   = lane * 4;

  const float* cb = caps   + (size_t)(bc * 16) * (K_ * DOUT_) + o4;
  const float* mb = mapped + ((size_t)(bc * 16) * L_ + l0) * DOUT_ + o4;

  float acc[K_][4];
  #pragma unroll
  for (int k = 0; k < K_; ++k)
    #pragma unroll
    for (int ll = 0; ll < 4; ++ll) acc[k][ll] = 0.f;

  float4 cA[K_], mA[4], cB[K_], mB[4];

#define LOADC(DST, BI) do { \
    const float* _p = cb + (size_t)(BI) * (K_ * DOUT_); \
    _Pragma("unroll") \
    for (int _k = 0; _k < K_; ++_k) DST[_k] = *(const float4*)(_p + _k * DOUT_); \
  } while (0)
#define LOADM(DST, BI) do { \
    const float* _p = mb + (size_t)(BI) * (L_ * DOUT_); \
    _Pragma("unroll") \
    for (int _l = 0; _l < 4; ++_l) DST[_l] = *(const float4*)(_p + _l * DOUT_); \
  } while (0)
#define COMPUTE(CC, MM) do { \
    _Pragma("unroll") \
    for (int _k = 0; _k < K_; ++_k) \
      _Pragma("unroll") \
      for (int _l = 0; _l < 4; ++_l) \
        acc[_k][_l] += CC[_k].x * MM[_l].x + CC[_k].y * MM[_l].y \
                     + CC[_k].z * MM[_l].z + CC[_k].w * MM[_l].w; \
  } while (0)

  LOADC(cA, 0); LOADM(mA, 0);
  for (int i = 0; i < 8; ++i) {           // 2 b per iteration, double-buffered
    LOADC(cB, 2 * i + 1); LOADM(mB, 2 * i + 1);
    COMPUTE(cA, mA);
    if (i < 7) { LOADC(cA, 2 * i + 2); LOADM(mA, 2 * i + 2); }
    COMPUTE(cB, mB);
  }
#undef LOADC
#undef LOADM
#undef COMPUTE

  // lane-reduce each (k,ll) over the 64 lanes (256 channels); lane k*4+ll keeps it
  float out = 0.f;
  #pragma unroll
  for (int k = 0; k < K_; ++k)
    #pragma unroll
    for (int ll = 0; ll < 4; ++ll) {
      float v = acc[k][ll];
      v += __shfl_xor(v, 1, 64);
      v += __shfl_xor(v, 2, 64);
      v += __shfl_xor(v, 4, 64);
      v += __shfl_xor(v, 8, 64);
      v += __shfl_xor(v, 16, 64);
      v += __shfl_xor(v, 32, 64);
      if (lane == k * 4 + ll) out = v;
    }
  // lanes 0..31 own (k = lane>>2, l = l0 + (lane&3)); exact fixed-point accumulate
  if (lane < 32) {
    long long q = llrintf(out * DSCALE);
    atomicAdd((unsigned long long*)&accOut[((size_t)(lane >> 2) * L_ + l0 + (lane & 3)) * 8],
              (unsigned long long)q);
  }
}

// ---------------- zero the three int64 accumulator buffers (38400 entries)
__global__ __launch_bounds__(256)
void init_acc(long long* __restrict__ a)
{
  int i = blockIdx.x * 256 + threadIdx.x;
  a[i] = 0;
}

extern "C" void kernel_launch(void* const* d_in, const int* in_sizes, int n_in,
                              void* d_out, int out_size, void* d_ws, size_t ws_size,
                              hipStream_t stream)
{
  const float* behav = (const float*)d_in[0];
  const int*   slen  = (const int*)d_in[1];
  const float* rlog  = (const float*)d_in[2];
  const float* W     = (const float*)d_in[3];
  float* caps = (float*)d_out;

  char* ws = (char*)d_ws;
  // acc buffers: 1600 counters padded to one 64B line each -> 102400 B apiece
  long long* z0   = (long long*)ws;                      // always-zero
  long long* acc0 = (long long*)(ws + 102400);
  long long* acc1 = (long long*)(ws + 204800);           // ends 307200
  unsigned short* Wh = (unsigned short*)(ws + 327680);   // 128 KiB each
  unsigned short* Wm = (unsigned short*)(ws + 458752);
  unsigned short* Wl = (unsigned short*)(ws + 589824);   // ends 720896 < 1 MiB
  float* mapped   = (float*)(ws + (1 << 20));            // 200 MiB fp32

  init_acc<<<dim3(150), 256, 0, stream>>>((long long*)ws);   // zeroes z0,acc0,acc1
  wt_prep<<<dim3(256), 256, 0, stream>>>(W, Wh, Wm, Wl);
  gemm_mapped<<<dim3(3200), 256, 0, stream>>>(behav, Wh, Wm, Wl, mapped);

  // it0: logits = rlog               -> caps, then delta -> acc0
  z_soft<<<dim3(B_), 256, 0, stream>>>(mapped, rlog, z0,   z0,   slen, caps);
  delta_kernel<<<dim3(800), 256, 0, stream>>>(mapped, caps, acc0);
  // it1: logits = rlog + acc0        -> caps, then delta -> acc1
  z_soft<<<dim3(B_), 256, 0, stream>>>(mapped, rlog, acc0, z0,   slen, caps);
  delta_kernel<<<dim3(800), 256, 0, stream>>>(mapped, caps, acc1);
  // it2: logits = rlog + acc0 + acc1 -> final caps
  z_soft<<<dim3(B_), 256, 0, stream>>>(mapped, rlog, acc0, acc1, slen, caps);
}

// Round 6
// 556.807 us; speedup vs baseline: 1.2852x; 1.0382x over previous
//
#include <hip/hip_runtime.h>
#include <cstdint>
#include <cstddef>

#define B_    1024
#define L_    200
#define DIN_  256
#define DOUT_ 256
#define K_    8
#define M_    (B_ * L_)   // 204800

typedef __attribute__((ext_vector_type(8))) short bf16x8;
typedef __attribute__((ext_vector_type(4))) float f32x4;

__device__ __forceinline__ float bf2f(unsigned short u) {
  union { unsigned int i; float f; } w; w.i = ((unsigned int)u) << 16; return w.f;
}
__device__ __forceinline__ unsigned short f2bf(float f) {
  union { float f; unsigned int i; } w; w.f = f;
  unsigned int x = w.i;
  return (unsigned short)((x + 0x7fffu + ((x >> 16) & 1u)) >> 16);
}

// async 16B global -> LDS copy (wave-uniform LDS base + lane*16 pattern)
__device__ __forceinline__ void gload16(const void* g, void* l) {
  __builtin_amdgcn_global_load_lds(
      (const __attribute__((address_space(1))) unsigned int*)g,
      (__attribute__((address_space(3))) unsigned int*)l, 16, 0, 0);
}

// ---------------- kernel 0: split W into bf16 hi/mid/lo in MFMA FRAGMENT ORDER.
__global__ __launch_bounds__(256)
void wt_prep(const float* __restrict__ W, unsigned short* __restrict__ Wh,
             unsigned short* __restrict__ Wm, unsigned short* __restrict__ Wl)
{
  const int k = blockIdx.x;    // 256
  const int n = threadIdx.x;   // 256
  float x = W[k * DOUT_ + n];
  unsigned short h = f2bf(x);
  float r = x - bf2f(h);
  unsigned short m = f2bf(r);
  float r2 = r - bf2f(m);
  unsigned short l = f2bf(r2);
  const int k0b = k >> 5, quad = (k >> 3) & 3, j = k & 7;
  const int nt = n >> 4, lr = n & 15;
  const size_t idx = ((((size_t)k0b * 16 + nt) * 64) + (quad * 16 + lr)) * 8 + j;
  Wh[idx] = h;
  Wm[idx] = m;
  Wl[idx] = l;
}

// ---------------- kernel 1: mapped = A @ W via bf16x3-split MFMA.
// R5 version (183 us measured): m97-style LDS staging of B; 64x256 block,
// 4 waves (32x128 tile each); 48 KB LDS, 3 blocks/CU. UNCHANGED this round.
__global__ __launch_bounds__(256, 3)
void gemm_mapped(const float* __restrict__ A,
                 const unsigned short* __restrict__ Wh,
                 const unsigned short* __restrict__ Wm,
                 const unsigned short* __restrict__ Wl,
                 float* __restrict__ C)
{
  const int t    = threadIdx.x;
  const int wave = t >> 6;
  const int lane = t & 63;
  const int quad = lane >> 4;
  const int lr   = lane & 15;
  const int m0   = blockIdx.x * 64 + (wave & 1) * 32;
  const int nt0  = (wave >> 1) * 8;     // N-half: fragments nt0..nt0+7

  // 3 buffers (h/m/l) x 16 nt x 64 lanes x 8 shorts = 49152 B
  __shared__ unsigned short ldsB[3 * 16 * 64 * 8];

  f32x4 acc[2][8];
  #pragma unroll
  for (int mt = 0; mt < 2; ++mt)
    #pragma unroll
    for (int nt = 0; nt < 8; ++nt)
      acc[mt][nt] = (f32x4){0.f, 0.f, 0.f, 0.f};

  bf16x8 ah[2], am[2], al[2];
  float4 Af[2][2];

  const float* ap0 = A + (size_t)(m0 + lr) * DIN_ + quad * 8;
  const float* ap1 = A + (size_t)(m0 + 16 + lr) * DIN_ + quad * 8;

  // stage one k0b slice (16 KB per buffer): 4 rounds x 3 buffers per thread
#define STAGE(K0B) do { \
    const size_t _k = (size_t)(K0B) * 8192; \
    _Pragma("unroll") \
    for (int _r = 0; _r < 4; ++_r) { \
      gload16(Wh + _k + _r * 2048 + t * 8, ldsB +         _r * 2048 + t * 8); \
      gload16(Wm + _k + _r * 2048 + t * 8, ldsB +  8192 + _r * 2048 + t * 8); \
      gload16(Wl + _k + _r * 2048 + t * 8, ldsB + 16384 + _r * 2048 + t * 8); \
    } \
  } while (0)

  // prologue: A raw for k0b=0; stage B k0b=0
  Af[0][0] = *(const float4*)(ap0);
  Af[0][1] = *(const float4*)(ap0 + 4);
  Af[1][0] = *(const float4*)(ap1);
  Af[1][1] = *(const float4*)(ap1 + 4);
  STAGE(0);
  asm volatile("s_waitcnt vmcnt(0)" ::: "memory");
  __syncthreads();

  for (int k0b = 0; k0b < 8; ++k0b) {
    // convert prefetched A to bf16x3 fragments
    #pragma unroll
    for (int mt = 0; mt < 2; ++mt) {
      float xs[8] = {Af[mt][0].x, Af[mt][0].y, Af[mt][0].z, Af[mt][0].w,
                     Af[mt][1].x, Af[mt][1].y, Af[mt][1].z, Af[mt][1].w};
      #pragma unroll
      for (int j = 0; j < 8; ++j) {
        unsigned short h = f2bf(xs[j]);
        float r = xs[j] - bf2f(h);
        unsigned short mm = f2bf(r);
        float r2 = r - bf2f(mm);
        unsigned short ll = f2bf(r2);
        ah[mt][j] = (short)h; am[mt][j] = (short)mm; al[mt][j] = (short)ll;
      }
    }
    // issue next k0's A raw loads (drained by the staging vmcnt(0) below)
    if (k0b < 7) {
      const int ko = (k0b + 1) * 32;
      Af[0][0] = *(const float4*)(ap0 + ko);
      Af[0][1] = *(const float4*)(ap0 + ko + 4);
      Af[1][0] = *(const float4*)(ap1 + ko);
      Af[1][1] = *(const float4*)(ap1 + ko + 4);
    }

#define GROUP(NT) do { \
    const unsigned short* _lb = ldsB + (size_t)((nt0 + (NT)) * 64 + lane) * 8; \
    bf16x8 Bh_ = *(const bf16x8*)(_lb); \
    bf16x8 Bm_ = *(const bf16x8*)(_lb + 8192); \
    bf16x8 Bl_ = *(const bf16x8*)(_lb + 16384); \
    f32x4 c0 = acc[0][NT], c1 = acc[1][NT]; \
    c0 = __builtin_amdgcn_mfma_f32_16x16x32_bf16(ah[0], Bh_, c0, 0, 0, 0); \
    c1 = __builtin_amdgcn_mfma_f32_16x16x32_bf16(ah[1], Bh_, c1, 0, 0, 0); \
    c0 = __builtin_amdgcn_mfma_f32_16x16x32_bf16(ah[0], Bm_, c0, 0, 0, 0); \
    c1 = __builtin_amdgcn_mfma_f32_16x16x32_bf16(ah[1], Bm_, c1, 0, 0, 0); \
    c0 = __builtin_amdgcn_mfma_f32_16x16x32_bf16(am[0], Bh_, c0, 0, 0, 0); \
    c1 = __builtin_amdgcn_mfma_f32_16x16x32_bf16(am[1], Bh_, c1, 0, 0, 0); \
    c0 = __builtin_amdgcn_mfma_f32_16x16x32_bf16(ah[0], Bl_, c0, 0, 0, 0); \
    c1 = __builtin_amdgcn_mfma_f32_16x16x32_bf16(ah[1], Bl_, c1, 0, 0, 0); \
    c0 = __builtin_amdgcn_mfma_f32_16x16x32_bf16(am[0], Bm_, c0, 0, 0, 0); \
    c1 = __builtin_amdgcn_mfma_f32_16x16x32_bf16(am[1], Bm_, c1, 0, 0, 0); \
    c0 = __builtin_amdgcn_mfma_f32_16x16x32_bf16(al[0], Bh_, c0, 0, 0, 0); \
    c1 = __builtin_amdgcn_mfma_f32_16x16x32_bf16(al[1], Bh_, c1, 0, 0, 0); \
    acc[0][NT] = c0; acc[1][NT] = c1; \
  } while (0)

    GROUP(0); GROUP(1); GROUP(2); GROUP(3);
    GROUP(4); GROUP(5); GROUP(6); GROUP(7);
#undef GROUP

    __syncthreads();                      // all waves done reading this slice
    if (k0b < 7) {
      STAGE(k0b + 1);
      asm volatile("s_waitcnt vmcnt(0)" ::: "memory");
      __syncthreads();                    // staged slice visible to all
    }
  }
#undef STAGE

  // C/D layout: row = quad*4 + reg, col = lr (within each 16x16 tile)
  #pragma unroll
  for (int mt = 0; mt < 2; ++mt)
    #pragma unroll
    for (int nt = 0; nt < 8; ++nt)
      #pragma unroll
      for (int r = 0; r < 4; ++r) {
        int row = m0 + mt * 16 + quad * 4 + r;
        C[(size_t)row * DOUT_ + (nt0 + nt) * 16 + lr] = acc[mt][nt][r];
      }
}

// ---------------- z_soft: softmax + Z + squash, one block per b, 4 waves.
// logits reconstructed in-kernel: rlog + (accA+accB) * 2^-26 (exact int64 partials).
// R6: phase B unrolled 4 rows/iter (4 independent loads in flight -> hides
// L3/HBM latency). Rows >= len have weight exactly 0 in wsmT, so padded rows
// contribute exact +0.0; indices >= 200 are address-clamped with weight zeroed.
// FMA order per accumulator chain unchanged -> bit-identical output.
#define DSCALE     67108864.0f            // 2^26
#define DSCALE_INV 1.4901161193847656e-8f // 2^-26

__global__ __launch_bounds__(256, 4)
void z_soft(const float* __restrict__ mapped,
            const float* __restrict__ rlog,
            const long long* __restrict__ accA,
            const long long* __restrict__ accB,
            const int* __restrict__ seq_len,
            float* __restrict__ caps)
{
  const int t    = threadIdx.x;
  const int lane = t & 63;
  const int wave = t >> 6;
  const int b    = blockIdx.x;
  const int len  = seq_len[b];            // 1..200

  __shared__ float wsmT[200][8];          // weights, transposed [l][k]  (6400 B)
  __shared__ float zred[2][8][256];       // Z cross-wave reduction     (16384 B)
  __shared__ float sqred[4][8];           // squash norm partials         (128 B)

  // ---- Phase A: masked softmax; wave w owns k = 2w, 2w+1
  #pragma unroll
  for (int kk = 0; kk < 2; ++kk) {
    const int k = wave * 2 + kk;
    float v[4];
    float mx = -3.4028235e38f;
    #pragma unroll
    for (int i = 0; i < 4; ++i) {
      int l = lane + 64 * i;
      float lv = -3.4028235e38f;
      if (l < len) {
        long long a = accA[(k * L_ + l) * 8] + accB[(k * L_ + l) * 8];
        lv = rlog[k * L_ + l] + (float)a * DSCALE_INV;
      }
      v[i] = lv;
      mx = fmaxf(mx, lv);
    }
    #pragma unroll
    for (int s = 1; s < 64; s <<= 1) mx = fmaxf(mx, __shfl_xor(mx, s, 64));
    float e[4]; float sum = 0.f;
    #pragma unroll
    for (int i = 0; i < 4; ++i) {
      int l = lane + 64 * i;
      e[i] = (l < len) ? __expf(v[i] - mx) : 0.f;
      sum += e[i];
    }
    #pragma unroll
    for (int s = 1; s < 64; s <<= 1) sum += __shfl_xor(sum, s, 64);
    float inv = 1.f / sum;
    #pragma unroll
    for (int i = 0; i < 4; ++i) {
      int l = lane + 64 * i;
      if (l < L_) wsmT[l][k] = e[i] * inv;
    }
  }
  __syncthreads();

  // ---- Phase B: Z partial; wave w handles rows l == w (mod 4), 4 rows/iter
  f32x4 zacc[K_];
  #pragma unroll
  for (int k = 0; k < K_; ++k) zacc[k] = (f32x4){0.f, 0.f, 0.f, 0.f};

  const float* mp = mapped + (size_t)b * (L_ * DOUT_) + lane * 4;
  for (int l = wave; l < len; l += 16) {
    // 4 candidate rows l, l+4, l+8, l+12; clamp addresses >=200, zero weights
    int  li[4];
    bool vi[4];
    #pragma unroll
    for (int r = 0; r < 4; ++r) {
      int lr_ = l + 4 * r;
      vi[r] = (lr_ < L_);
      li[r] = vi[r] ? lr_ : (L_ - 1);
    }
    f32x4 m[4];
    #pragma unroll
    for (int r = 0; r < 4; ++r)
      m[r] = *(const f32x4*)(mp + (size_t)li[r] * DOUT_);
    #pragma unroll
    for (int r = 0; r < 4; ++r) {
      float4 w0 = *(const float4*)&wsmT[li[r]][0];
      float4 w1 = *(const float4*)&wsmT[li[r]][4];
      if (!vi[r]) {
        w0.x = w0.y = w0.z = w0.w = 0.f;
        w1.x = w1.y = w1.z = w1.w = 0.f;
      }
      zacc[0] += w0.x * m[r]; zacc[1] += w0.y * m[r];
      zacc[2] += w0.z * m[r]; zacc[3] += w0.w * m[r];
      zacc[4] += w1.x * m[r]; zacc[5] += w1.y * m[r];
      zacc[6] += w1.z * m[r]; zacc[7] += w1.w * m[r];
    }
  }

  // two-stage cross-wave reduce
  if (wave >= 2) {
    #pragma unroll
    for (int k = 0; k < K_; ++k)
      *(f32x4*)&zred[wave - 2][k][lane * 4] = zacc[k];
  }
  __syncthreads();
  if (wave < 2) {
    #pragma unroll
    for (int k = 0; k < K_; ++k) {
      f32x4 r = *(const f32x4*)&zred[wave][k][lane * 4];
      r += zacc[k];
      *(f32x4*)&zred[wave][k][lane * 4] = r;
    }
  }
  __syncthreads();

  // ---- Phase C: combine + squash; thread t owns channel t
  float z[K_];
  #pragma unroll
  for (int k = 0; k < K_; ++k) z[k] = zred[0][k][t] + zred[1][k][t];

  #pragma unroll
  for (int k = 0; k < K_; ++k) {
    float s2 = z[k] * z[k];
    #pragma unroll
    for (int s = 1; s < 64; s <<= 1) s2 += __shfl_xor(s2, s, 64);
    if (lane == 0) sqred[wave][k] = s2;
  }
  __syncthreads();
  #pragma unroll
  for (int k = 0; k < K_; ++k) {
    float sq = sqred[0][k] + sqred[1][k] + sqred[2][k] + sqred[3][k];
    float scale = sq / ((1.f + sq) * sqrtf(sq + 1e-8f));
    caps[((size_t)b * K_ + k) * DOUT_ + t] = scale * z[k];
  }
}

// ---------------- delta: register-blocked over 16 b x 4 l per wave.
// Grid 800 -> ~3.1 waves/SIMD. Per-(k,l) partials are 16-b sums -> int64 exact.
__global__ __launch_bounds__(256)
void delta_kernel(const float* __restrict__ mapped, const float* __restrict__ caps,
                  long long* __restrict__ accOut)
{
  const int t    = threadIdx.x;
  const int lane = t & 63;
  const int wave = t >> 6;
  const int wid  = blockIdx.x * 4 + wave;   // 0..3199
  const int lc   = wid % 50;                // l-chunk: 4 l's
  const int bc   = wid / 50;                // b-chunk: 16 b's (0..63)
  const int l0   = lc * 4;
  const int o4   = lane * 4;

  const float* cb = caps   + (size_t)(bc * 16) * (K_ * DOUT_) + o4;
  const float* mb = mapped + ((size_t)(bc * 16) * L_ + l0) * DOUT_ + o4;

  float acc[K_][4];
  #pragma unroll
  for (int k = 0; k < K_; ++k)
    #pragma unroll
    for (int ll = 0; ll < 4; ++ll) acc[k][ll] = 0.f;

  float4 cA[K_], mA[4], cB[K_], mB[4];

#define LOADC(DST, BI) do { \
    const float* _p = cb + (size_t)(BI) * (K_ * DOUT_); \
    _Pragma("unroll") \
    for (int _k = 0; _k < K_; ++_k) DST[_k] = *(const float4*)(_p + _k * DOUT_); \
  } while (0)
#define LOADM(DST, BI) do { \
    const float* _p = mb + (size_t)(BI) * (L_ * DOUT_); \
    _Pragma("unroll") \
    for (int _l = 0; _l < 4; ++_l) DST[_l] = *(const float4*)(_p + _l * DOUT_); \
  } while (0)
#define COMPUTE(CC, MM) do { \
    _Pragma("unroll") \
    for (int _k = 0; _k < K_; ++_k) \
      _Pragma("unroll") \
      for (int _l = 0; _l < 4; ++_l) \
        acc[_k][_l] += CC[_k].x * MM[_l].x + CC[_k].y * MM[_l].y \
                     + CC[_k].z * MM[_l].z + CC[_k].w * MM[_l].w; \
  } while (0)

  LOADC(cA, 0); LOADM(mA, 0);
  for (int i = 0; i < 8; ++i) {           // 2 b per iteration, double-buffered
    LOADC(cB, 2 * i + 1); LOADM(mB, 2 * i + 1);
    COMPUTE(cA, mA);
    if (i < 7) { LOADC(cA, 2 * i + 2); LOADM(mA, 2 * i + 2); }
    COMPUTE(cB, mB);
  }
#undef LOADC
#undef LOADM
#undef COMPUTE

  // lane-reduce each (k,ll) over the 64 lanes (256 channels); lane k*4+ll keeps it
  float out = 0.f;
  #pragma unroll
  for (int k = 0; k < K_; ++k)
    #pragma unroll
    for (int ll = 0; ll < 4; ++ll) {
      float v = acc[k][ll];
      v += __shfl_xor(v, 1, 64);
      v += __shfl_xor(v, 2, 64);
      v += __shfl_xor(v, 4, 64);
      v += __shfl_xor(v, 8, 64);
      v += __shfl_xor(v, 16, 64);
      v += __shfl_xor(v, 32, 64);
      if (lane == k * 4 + ll) out = v;
    }
  // lanes 0..31 own (k = lane>>2, l = l0 + (lane&3)); exact fixed-point accumulate
  if (lane < 32) {
    long long q = llrintf(out * DSCALE);
    atomicAdd((unsigned long long*)&accOut[((size_t)(lane >> 2) * L_ + l0 + (lane & 3)) * 8],
              (unsigned long long)q);
  }
}

// ---------------- zero the three int64 accumulator buffers (38400 entries)
__global__ __launch_bounds__(256)
void init_acc(long long* __restrict__ a)
{
  int i = blockIdx.x * 256 + threadIdx.x;
  a[i] = 0;
}

extern "C" void kernel_launch(void* const* d_in, const int* in_sizes, int n_in,
                              void* d_out, int out_size, void* d_ws, size_t ws_size,
                              hipStream_t stream)
{
  const float* behav = (const float*)d_in[0];
  const int*   slen  = (const int*)d_in[1];
  const float* rlog  = (const float*)d_in[2];
  const float* W     = (const float*)d_in[3];
  float* caps = (float*)d_out;

  char* ws = (char*)d_ws;
  // acc buffers: 1600 counters padded to one 64B line each -> 102400 B apiece
  long long* z0   = (long long*)ws;                      // always-zero
  long long* acc0 = (long long*)(ws + 102400);
  long long* acc1 = (long long*)(ws + 204800);           // ends 307200
  unsigned short* Wh = (unsigned short*)(ws + 327680);   // 128 KiB each
  unsigned short* Wm = (unsigned short*)(ws + 458752);
  unsigned short* Wl = (unsigned short*)(ws + 589824);   // ends 720896 < 1 MiB
  float* mapped   = (float*)(ws + (1 << 20));            // 200 MiB fp32

  init_acc<<<dim3(150), 256, 0, stream>>>((long long*)ws);   // zeroes z0,acc0,acc1
  wt_prep<<<dim3(256), 256, 0, stream>>>(W, Wh, Wm, Wl);
  gemm_mapped<<<dim3(3200), 256, 0, stream>>>(behav, Wh, Wm, Wl, mapped);

  // it0: logits = rlog               -> caps, then delta -> acc0
  z_soft<<<dim3(B_), 256, 0, stream>>>(mapped, rlog, z0,   z0,   slen, caps);
  delta_kernel<<<dim3(800), 256, 0, stream>>>(mapped, caps, acc0);
  // it1: logits = rlog + acc0        -> caps, then delta -> acc1
  z_soft<<<dim3(B_), 256, 0, stream>>>(mapped, rlog, acc0, z0,   slen, caps);
  delta_kernel<<<dim3(800), 256, 0, stream>>>(mapped, caps, acc1);
  // it2: logits = rlog + acc0 + acc1 -> final caps
  z_soft<<<dim3(B_), 256, 0, stream>>>(mapped, rlog, acc0, acc1, slen, caps);
}